// Round 1
// baseline (1117.554 us; speedup 1.0000x reference)
//
#include <hip/hip_runtime.h>

#define SEQ_LEN 128
#define IN_FEATS 2
#define HID 32

// ---------------- GCN phase ----------------

// Count in-degree at dst (int atomics into ws buffer).
__global__ void count_kernel(const int* __restrict__ idx, int E, int* __restrict__ cnt) {
    int e = blockIdx.x * blockDim.x + threadIdx.x;
    if (e < E) atomicAdd(&cnt[idx[E + e]], 1);
}

// In-place: buf held int counts (bit pattern); replace with rsqrt(count+1).
__global__ void dinv_kernel(float* __restrict__ buf, int n) {
    int i = blockIdx.x * blockDim.x + threadIdx.x;
    if (i < n) {
        int c = __float_as_int(buf[i]);
        buf[i] = rsqrtf((float)c + 1.0f);
    }
}

// Scatter pre-transform features: agg2[dst] += x[src] * (dinv[src]*dinv[dst]).
// Linearity: (sum x[src]*norm) @ W == sum (x[src]@W)*norm  -> 16x fewer atomics.
__global__ void scatter_kernel(const int* __restrict__ idx, int E,
                               const float2* __restrict__ x2,
                               const float* __restrict__ dinv,
                               float* __restrict__ agg2) {
    int e = blockIdx.x * blockDim.x + threadIdx.x;
    if (e < E) {
        int s = idx[e];
        int d = idx[E + e];
        float norm = dinv[s] * dinv[d];
        float2 xs = x2[s];
        atomicAdd(&agg2[2 * d + 0], xs.x * norm);
        atomicAdd(&agg2[2 * d + 1], xs.y * norm);
    }
}

// ---------------- fused GCN-epilogue + LSTM + FC ----------------
// One wave (64 lanes) per node. Lane l owns gate rows l and l+64 of the 4H=128
// gate vector (rows 0..31=i, 32..63=f, 64..95=g, 96..127=o):
//   lane l<32  : i[l]  and g[l]
//   lane l>=32 : f[l-32] and o[l-32]
// Weights for the two owned rows live in registers (32 float4 = 128 VGPR).
// xg_t and h_t are broadcast from LDS (same-address ds_read_b128 = free).
__global__ __launch_bounds__(64) void lstm_kernel(
    const float2* __restrict__ x2, const float* __restrict__ dinv,
    const float2* __restrict__ agg2,
    const float* __restrict__ gcn_W, const float* __restrict__ gcn_b,
    const float* __restrict__ w_ih, const float* __restrict__ w_hh,
    const float* __restrict__ b_ih, const float* __restrict__ b_hh,
    const float* __restrict__ fc_W, const float* __restrict__ fc_b,
    float* __restrict__ out) {
    __shared__ float2 uarr[SEQ_LEN];   // pre-GCN-linear 2-vec per timestep
    __shared__ float4 xgbuf[HID / 4];  // xg_t (32 floats)
    __shared__ float4 hbuf[HID / 4];   // h_t  (32 floats)

    const int node = blockIdx.x;
    const int lane = threadIdx.x;
    const int k = lane & 31;
    const bool lo = lane < 32;
    const int rbase = node * SEQ_LEN;

    // Phase A: u[t] = agg2[r] + x[r] * (1/deg[r]),  1/deg = dinv^2
    #pragma unroll
    for (int p = 0; p < 2; ++p) {
        int t = lane + p * 64;
        int r = rbase + t;
        float dv = dinv[r];
        float idv = dv * dv;
        float2 a = agg2[r];
        float2 xx = x2[r];
        uarr[t] = make_float2(fmaf(xx.x, idv, a.x), fmaf(xx.y, idv, a.y));
    }

    // Per-lane weights: rows (lane) and (lane+64) of w_ih / w_hh.
    float4 wia[8], wib[8], wha[8], whb[8];
    const float4* wi4 = reinterpret_cast<const float4*>(w_ih);
    const float4* wh4 = reinterpret_cast<const float4*>(w_hh);
    #pragma unroll
    for (int kk = 0; kk < 8; ++kk) {
        wia[kk] = wi4[lane * 8 + kk];
        wib[kk] = wi4[(lane + 64) * 8 + kk];
        wha[kk] = wh4[lane * 8 + kk];
        whb[kk] = wh4[(lane + 64) * 8 + kk];
    }
    const float bsa = b_ih[lane] + b_hh[lane];
    const float bsb = b_ih[lane + 64] + b_hh[lane + 64];

    // GCN linear constants for lanes<32 (column k of W, bias k).
    const float W0 = gcn_W[k];
    const float W1 = gcn_W[HID + k];
    const float gb = gcn_b[k];

    // act_b: lanes<32 need tanh(g) = 2*sigm(2g)-1; lanes>=32 need sigm(o).
    const float nb_scale = lo ? -2.0f : -1.0f;
    const float mb = lo ? 2.0f : 1.0f;
    const float ab = lo ? -1.0f : 0.0f;

    if (lo) ((float*)hbuf)[k] = 0.0f;
    float c = 0.0f;
    float hn = 0.0f;
    __syncthreads();

    for (int t = 0; t < SEQ_LEN; ++t) {
        if (lo) {
            float2 u = uarr[t];
            float xg = fmaf(u.x, W0, fmaf(u.y, W1, gb));
            ((float*)xgbuf)[k] = fmaxf(xg, 0.0f);
        }
        __syncthreads();

        float axa = 0.0f, aha = 0.0f, axb = 0.0f, ahb = 0.0f;  // 4 indep chains
        #pragma unroll
        for (int kk = 0; kk < 8; ++kk) {
            float4 xv = xgbuf[kk];
            float4 hv = hbuf[kk];
            axa = fmaf(xv.x, wia[kk].x, axa);
            axa = fmaf(xv.y, wia[kk].y, axa);
            axa = fmaf(xv.z, wia[kk].z, axa);
            axa = fmaf(xv.w, wia[kk].w, axa);
            aha = fmaf(hv.x, wha[kk].x, aha);
            aha = fmaf(hv.y, wha[kk].y, aha);
            aha = fmaf(hv.z, wha[kk].z, aha);
            aha = fmaf(hv.w, wha[kk].w, aha);
            axb = fmaf(xv.x, wib[kk].x, axb);
            axb = fmaf(xv.y, wib[kk].y, axb);
            axb = fmaf(xv.z, wib[kk].z, axb);
            axb = fmaf(xv.w, wib[kk].w, axb);
            ahb = fmaf(hv.x, whb[kk].x, ahb);
            ahb = fmaf(hv.y, whb[kk].y, ahb);
            ahb = fmaf(hv.z, whb[kk].z, ahb);
            ahb = fmaf(hv.w, whb[kk].w, ahb);
        }
        float ga = bsa + axa + aha;   // row lane   : i (lo) / f (hi)
        float gbv = bsb + axb + ahb;  // row lane+64: g (lo) / o (hi)

        float ea = __expf(-ga);
        float act_a = __fdividef(1.0f, 1.0f + ea);            // sigmoid
        float eb = __expf(gbv * nb_scale);
        float act_b = fmaf(__fdividef(1.0f, 1.0f + eb), mb, ab);  // tanh or sigm

        float oth_a = __shfl_xor(act_a, 32);
        float oth_b = __shfl_xor(act_b, 32);
        float ii = lo ? act_a : oth_a;
        float gg = lo ? act_b : oth_b;
        float ff = lo ? oth_a : act_a;
        float oo = lo ? oth_b : act_b;

        c = fmaf(ff, c, ii * gg);
        float ec = __expf(-2.0f * c);
        float th = fmaf(__fdividef(1.0f, 1.0f + ec), 2.0f, -1.0f);  // tanh(c)
        hn = oo * th;

        __syncthreads();
        if (lo) ((float*)hbuf)[k] = hn;
    }

    // FC epilogue: out[node] = dot(h_n, fc_W) + fc_b. Both wave halves hold
    // identical per-unit hn; reduce within 32 lanes, lane 0 writes.
    float val = hn * fc_W[k];
    #pragma unroll
    for (int off = 16; off; off >>= 1) val += __shfl_xor(val, off);
    if (lane == 0) out[node] = val + fc_b[0];
}

extern "C" void kernel_launch(void* const* d_in, const int* in_sizes, int n_in,
                              void* d_out, int out_size, void* d_ws, size_t ws_size,
                              hipStream_t stream) {
    const float* x     = (const float*)d_in[0];
    const int*   idx   = (const int*)d_in[1];
    const float* gcn_W = (const float*)d_in[2];
    const float* gcn_b = (const float*)d_in[3];
    const float* w_ih  = (const float*)d_in[4];
    const float* w_hh  = (const float*)d_in[5];
    const float* b_ih  = (const float*)d_in[6];
    const float* b_hh  = (const float*)d_in[7];
    const float* fc_W  = (const float*)d_in[8];
    const float* fc_b  = (const float*)d_in[9];

    const int num_nodes = in_sizes[0] / (SEQ_LEN * IN_FEATS);
    const int ntot = num_nodes * SEQ_LEN;
    const int E = in_sizes[1] / 2;

    // ws layout: [dinv: ntot floats][agg2: ntot float2]
    float* dinv = (float*)d_ws;
    float* agg2 = dinv + ntot;

    hipMemsetAsync(d_ws, 0, (size_t)ntot * sizeof(float) * 3, stream);

    count_kernel<<<(E + 255) / 256, 256, 0, stream>>>(idx, E, (int*)dinv);
    dinv_kernel<<<(ntot + 255) / 256, 256, 0, stream>>>(dinv, ntot);
    scatter_kernel<<<(E + 255) / 256, 256, 0, stream>>>(
        idx, E, (const float2*)x, dinv, agg2);
    lstm_kernel<<<num_nodes, 64, 0, stream>>>(
        (const float2*)x, dinv, (const float2*)agg2,
        gcn_W, gcn_b, w_ih, w_hh, b_ih, b_hh, fc_W, fc_b,
        (float*)d_out);
}